// Round 1
// baseline (591.966 us; speedup 1.0000x reference)
//
#include <hip/hip_runtime.h>
#include <hip/hip_bf16.h>

#define BB   16
#define SS   512
#define DD   768
#define NHH  4
#define HDD  192
#define DFFD 2048
#define NID  18
#define NW   510          // S - W + 1
#define NWIN (BB * NW)    // 8160 windows
#define MR   (NWIN * 3)   // 24480 encoder rows

typedef __attribute__((ext_vector_type(8))) short bf16x8;
typedef __attribute__((ext_vector_type(4))) float f32x4;
typedef __hip_bfloat16 bf16;

__device__ __forceinline__ float b2f(bf16 x) { return __bfloat162float(x); }

// ---------------- f32 -> bf16 conversion (vectorized) ----------------
__global__ __launch_bounds__(256) void cvt4_kernel(const float4* __restrict__ in,
                                                   ushort4* __restrict__ out, int n4)
{
    for (int i = blockIdx.x * 256 + threadIdx.x; i < n4; i += gridDim.x * 256) {
        float4 f = in[i];
        ushort4 u;
        u.x = __builtin_bit_cast(unsigned short, __float2bfloat16(f.x));
        u.y = __builtin_bit_cast(unsigned short, __float2bfloat16(f.y));
        u.z = __builtin_bit_cast(unsigned short, __float2bfloat16(f.z));
        u.w = __builtin_bit_cast(unsigned short, __float2bfloat16(f.w));
        out[i] = u;
    }
}

// ---------------- bf16 NT GEMM: C[M,N] = A[M,K] * Bm[N,K]^T + bias ----------------
// m97-style: 128x128 tile, BK=32, 4 waves (2x2 of 64x64), global_load_lds width 16.
template<bool RELU>
__global__ void gemm_bt(const bf16* __restrict__ A, const bf16* __restrict__ Bm,
                        const float* __restrict__ bias, bf16* __restrict__ C,
                        int M, int N, int K)
{
    __shared__ __align__(16) bf16 As[128 * 32];
    __shared__ __align__(16) bf16 Bs[128 * 32];
    const int tid = threadIdx.x;
    const int ln  = tid & 63;
    const int wv  = tid >> 6;
    const int row0 = blockIdx.y * 128;
    const int col0 = blockIdx.x * 128;
    const int wm = (wv >> 1) * 64;
    const int wn = (wv & 1) * 64;
    const int lrow = ln & 15;
    const int koff = (ln >> 4) * 8;

    // staging: 512 chunks of 16B per tile; thread t covers chunk t and 256+t
    const int r0 = tid >> 2, c0 = (tid & 3) * 8;
    const int r1 = r0 + 64;
    const bf16* gA0 = A + (size_t)min(row0 + r0, M - 1) * K + c0;
    const bf16* gA1 = A + (size_t)min(row0 + r1, M - 1) * K + c0;
    const bf16* gB0 = Bm + (size_t)(col0 + r0) * K + c0;
    const bf16* gB1 = Bm + (size_t)(col0 + r1) * K + c0;
    bf16* lA0 = As + wv * 512;
    bf16* lA1 = As + 2048 + wv * 512;
    bf16* lB0 = Bs + wv * 512;
    bf16* lB1 = Bs + 2048 + wv * 512;

    f32x4 acc[4][4] = {};

    for (int k0 = 0; k0 < K; k0 += 32) {
        __builtin_amdgcn_global_load_lds((const __attribute__((address_space(1))) void*)(gA0 + k0),
                                         (__attribute__((address_space(3))) void*)lA0, 16, 0, 0);
        __builtin_amdgcn_global_load_lds((const __attribute__((address_space(1))) void*)(gA1 + k0),
                                         (__attribute__((address_space(3))) void*)lA1, 16, 0, 0);
        __builtin_amdgcn_global_load_lds((const __attribute__((address_space(1))) void*)(gB0 + k0),
                                         (__attribute__((address_space(3))) void*)lB0, 16, 0, 0);
        __builtin_amdgcn_global_load_lds((const __attribute__((address_space(1))) void*)(gB1 + k0),
                                         (__attribute__((address_space(3))) void*)lB1, 16, 0, 0);
        __syncthreads();
        bf16x8 av[4], bv[4];
        #pragma unroll
        for (int mi = 0; mi < 4; ++mi)
            av[mi] = *(const bf16x8*)(As + (wm + mi * 16 + lrow) * 32 + koff);
        #pragma unroll
        for (int ni = 0; ni < 4; ++ni)
            bv[ni] = *(const bf16x8*)(Bs + (wn + ni * 16 + lrow) * 32 + koff);
        #pragma unroll
        for (int mi = 0; mi < 4; ++mi)
            #pragma unroll
            for (int ni = 0; ni < 4; ++ni)
                acc[mi][ni] = __builtin_amdgcn_mfma_f32_16x16x32_bf16(av[mi], bv[ni], acc[mi][ni], 0, 0, 0);
        __syncthreads();
    }

    // epilogue: C/D layout col=lane&15, row=(lane>>4)*4+reg
    #pragma unroll
    for (int mi = 0; mi < 4; ++mi) {
        #pragma unroll
        for (int ni = 0; ni < 4; ++ni) {
            const int col = col0 + wn + ni * 16 + lrow;
            const float bb = bias[col];
            #pragma unroll
            for (int r = 0; r < 4; ++r) {
                const int row = row0 + wm + mi * 16 + (ln >> 4) * 4 + r;
                if (row < M) {
                    float v = acc[mi][ni][r] + bb;
                    if (RELU) v = fmaxf(v, 0.0f);
                    C[(size_t)row * N + col] = __float2bfloat16(v);
                }
            }
        }
    }
}

// ---------------- attention over W=3 per (window, head): one wave each ----------------
__global__ __launch_bounds__(256) void attn_kernel(const bf16* __restrict__ qkv, bf16* __restrict__ o)
{
    const int m  = blockIdx.x;
    const int h  = threadIdx.x >> 6;
    const int ln = threadIdx.x & 63;
    const int bb = m / NW, n = m - bb * NW;
    const size_t base = (size_t)(bb * SS + n) * (3 * DD) + h * HDD + ln;
    float q[3][3], k[3][3], v[3][3];
    #pragma unroll
    for (int j = 0; j < 3; ++j)
        #pragma unroll
        for (int t = 0; t < 3; ++t) {
            size_t idx = base + (size_t)j * (3 * DD) + t * 64;
            q[j][t] = b2f(qkv[idx]);
            k[j][t] = b2f(qkv[idx + DD]);
            v[j][t] = b2f(qkv[idx + 2 * DD]);
        }
    float s[3][3];
    #pragma unroll
    for (int i = 0; i < 3; ++i)
        #pragma unroll
        for (int j = 0; j < 3; ++j)
            s[i][j] = q[i][0] * k[j][0] + q[i][1] * k[j][1] + q[i][2] * k[j][2];
    #pragma unroll
    for (int off = 32; off >= 1; off >>= 1)
        #pragma unroll
        for (int i = 0; i < 3; ++i)
            #pragma unroll
            for (int j = 0; j < 3; ++j)
                s[i][j] += __shfl_xor(s[i][j], off);
    const float scale = 0.07216878364870322f; // 1/sqrt(192)
    float p[3][3];
    #pragma unroll
    for (int i = 0; i < 3; ++i) {
        float mx = fmaxf(s[i][0], fmaxf(s[i][1], s[i][2])) * scale;
        float e0 = expf(s[i][0] * scale - mx);
        float e1 = expf(s[i][1] * scale - mx);
        float e2 = expf(s[i][2] * scale - mx);
        float inv = 1.0f / (e0 + e1 + e2);
        p[i][0] = e0 * inv; p[i][1] = e1 * inv; p[i][2] = e2 * inv;
    }
    #pragma unroll
    for (int i = 0; i < 3; ++i)
        #pragma unroll
        for (int t = 0; t < 3; ++t) {
            float ov = p[i][0] * v[0][t] + p[i][1] * v[1][t] + p[i][2] * v[2][t];
            o[(size_t)(m * 3 + i) * DD + h * HDD + t * 64 + ln] = __float2bfloat16(ov);
        }
}

// ---------------- residual + LayerNorm (MODE1: hidden_f32 + oproj; MODE2: x + f) ----------------
template<int MODE>
__global__ __launch_bounds__(256) void ln_kernel(const bf16* __restrict__ xa,
                                                 const float* __restrict__ hid,
                                                 const bf16* __restrict__ xb,
                                                 const float* __restrict__ gamma,
                                                 const float* __restrict__ beta,
                                                 bf16* __restrict__ out)
{
    const int r = blockIdx.x;
    const int tid = threadIdx.x;
    const size_t rb = (size_t)r * DD;
    float v[3];
    if (MODE == 1) {
        const int m = r / 3, i = r - m * 3;
        const int bb = m / NW, n = m - bb * NW;
        const size_t hb = (size_t)(bb * SS + n + i) * DD;
        #pragma unroll
        for (int t = 0; t < 3; ++t) {
            const int d = tid + t * 256;
            v[t] = hid[hb + d] + b2f(xb[rb + d]);
        }
    } else {
        #pragma unroll
        for (int t = 0; t < 3; ++t) {
            const int d = tid + t * 256;
            v[t] = b2f(xa[rb + d]) + b2f(xb[rb + d]);
        }
    }
    float s1 = v[0] + v[1] + v[2];
    float s2 = v[0] * v[0] + v[1] * v[1] + v[2] * v[2];
    #pragma unroll
    for (int off = 32; off >= 1; off >>= 1) {
        s1 += __shfl_xor(s1, off);
        s2 += __shfl_xor(s2, off);
    }
    __shared__ float red[8];
    const int wvi = tid >> 6, lnn = tid & 63;
    if (lnn == 0) { red[wvi] = s1; red[4 + wvi] = s2; }
    __syncthreads();
    s1 = red[0] + red[1] + red[2] + red[3];
    s2 = red[4] + red[5] + red[6] + red[7];
    const float mean = s1 * (1.0f / 768.0f);
    const float var  = fmaxf(s2 * (1.0f / 768.0f) - mean * mean, 0.0f);
    const float inv  = rsqrtf(var + 1e-5f);
    #pragma unroll
    for (int t = 0; t < 3; ++t) {
        const int d = tid + t * 256;
        out[rb + d] = __float2bfloat16((v[t] - mean) * inv * gamma[d] + beta[d]);
    }
}

// ---------------- max-pool over 3 rows + align output ----------------
__global__ __launch_bounds__(256) void pool_kernel(const bf16* __restrict__ x2,
                                                   float* __restrict__ pooled,
                                                   float* __restrict__ align)
{
    const int m = blockIdx.x;
    const int bb = m / NW, n = m - bb * NW;
    const size_t base = (size_t)m * 3 * DD;
    const size_t ab = (size_t)bb * 512 * DD;
    #pragma unroll
    for (int t = 0; t < 3; ++t) {
        const int d = threadIdx.x + t * 256;
        float v0 = b2f(x2[base + d]);
        float v1 = b2f(x2[base + DD + d]);
        float v2 = b2f(x2[base + 2 * DD + d]);
        float v = fmaxf(v0, fmaxf(v1, v2));
        pooled[(size_t)m * DD + d] = v;
        align[ab + (size_t)(n + 1) * DD + d] = v;
        if (n == 0)      align[ab + d] = v;
        if (n == NW - 1) align[ab + (size_t)511 * DD + d] = v;
    }
}

// ---------------- intent head: pred[m,c] = pooled[m,:] . iw[c,:] + ib[c] ----------------
__global__ __launch_bounds__(256) void intent_kernel(const float* __restrict__ pooled,
                                                     const float* __restrict__ iw,
                                                     const float* __restrict__ ib,
                                                     float* __restrict__ out)
{
    const int m = blockIdx.x;
    const int wvi = threadIdx.x >> 6, ln = threadIdx.x & 63;
    for (int c = wvi; c < NID; c += 4) {
        float sum = 0.0f;
        for (int d = ln; d < DD; d += 64)
            sum += pooled[(size_t)m * DD + d] * iw[(size_t)c * DD + d];
        #pragma unroll
        for (int off = 32; off >= 1; off >>= 1)
            sum += __shfl_xor(sum, off);
        if (ln == 0) out[(size_t)m * NID + c] = sum + ib[c];
    }
}

// ---------------- window_num (as float) ----------------
__global__ void wn_kernel(const int* __restrict__ seq, float* __restrict__ out)
{
    const int t = threadIdx.x;
    if (t < BB) {
        int wn = seq[t] - 2;
        if (wn < 1) wn = 1;
        out[t] = (float)wn;
    }
}

extern "C" void kernel_launch(void* const* d_in, const int* in_sizes, int n_in,
                              void* d_out, int out_size, void* d_ws, size_t ws_size,
                              hipStream_t stream)
{
    const float* hidden   = (const float*)d_in[0];
    const int*   seq_lens = (const int*)d_in[1];
    const float* in_w     = (const float*)d_in[2];
    const float* in_b     = (const float*)d_in[3];
    const float* out_w    = (const float*)d_in[4];
    const float* out_b    = (const float*)d_in[5];
    const float* ln1_g    = (const float*)d_in[6];
    const float* ln1_bb   = (const float*)d_in[7];
    const float* ln2_g    = (const float*)d_in[8];
    const float* ln2_bb   = (const float*)d_in[9];
    const float* f1_w     = (const float*)d_in[10];
    const float* f1_b     = (const float*)d_in[11];
    const float* f2_w     = (const float*)d_in[12];
    const float* f2_b     = (const float*)d_in[13];
    const float* it_w     = (const float*)d_in[14];
    const float* it_b     = (const float*)d_in[15];

    char* ws = (char*)d_ws;
    bf16*  hid_bf   = (bf16*)(ws + 0);          // 12,582,912 B
    bf16*  win_bf   = (bf16*)(ws + 12582912);   //  3,538,944
    bf16*  wout_bf  = (bf16*)(ws + 16121856);   //  1,179,648
    bf16*  wf1_bf   = (bf16*)(ws + 17301504);   //  3,145,728
    bf16*  wf2_bf   = (bf16*)(ws + 20447232);   //  3,145,728
    bf16*  qkv_bf   = (bf16*)(ws + 23592960);   // 37,748,736 (reused for f)
    bf16*  f_bf     = qkv_bf;
    bf16*  o_bf     = (bf16*)(ws + 61341696);   // 37,601,280 (reused for x2)
    bf16*  x2_bf    = o_bf;
    bf16*  oproj_bf = (bf16*)(ws + 98942976);   // 37,601,280 (reused for pooled f32)
    float* pooled   = (float*)(ws + 98942976);
    bf16*  x_bf     = (bf16*)(ws + 136544256);  // 37,601,280
    bf16*  h_bf     = (bf16*)(ws + 174145536);  // FFN hidden (chunked vs ws_size)

    float* out_pred  = (float*)d_out;           // 146880
    float* out_wn    = out_pred + 146880;       // 16
    float* out_align = out_pred + 146896;       // 6,291,456

    // f32 -> bf16
    cvt4_kernel<<<1024, 256, 0, stream>>>((const float4*)hidden, (ushort4*)hid_bf, 1572864);
    cvt4_kernel<<<512, 256, 0, stream>>>((const float4*)in_w,  (ushort4*)win_bf,  442368);
    cvt4_kernel<<<256, 256, 0, stream>>>((const float4*)out_w, (ushort4*)wout_bf, 147456);
    cvt4_kernel<<<512, 256, 0, stream>>>((const float4*)f1_w,  (ushort4*)wf1_bf,  393216);
    cvt4_kernel<<<512, 256, 0, stream>>>((const float4*)f2_w,  (ushort4*)wf2_bf,  393216);

    // QKV (per-position, shared across windows): [8192,768] x [2304,768]^T
    gemm_bt<false><<<dim3(18, 64), 256, 0, stream>>>(hid_bf, win_bf, in_b, qkv_bf, 8192, 2304, 768);
    // attention per (window, head)
    attn_kernel<<<NWIN, 256, 0, stream>>>(qkv_bf, o_bf);
    // out_proj: [24480,768] x [768,768]^T
    gemm_bt<false><<<dim3(6, 192), 256, 0, stream>>>(o_bf, wout_bf, out_b, oproj_bf, MR, 768, 768);
    // x = LN1(win + oproj)
    ln_kernel<1><<<MR, 256, 0, stream>>>(nullptr, hidden, oproj_bf, ln1_g, ln1_bb, x_bf);

    // FFN, chunked over rows so the 2048-wide hidden fits in remaining workspace
    size_t avail = ws_size > 174145536ull ? ws_size - 174145536ull : 0;
    long cap = (long)(avail / (DFFD * 2));
    cap = (cap / 128) * 128;
    if (cap < 128) cap = 128;
    if (cap > MR) cap = MR;
    for (int r0 = 0; r0 < MR; r0 += (int)cap) {
        int mc = MR - r0; if (mc > cap) mc = (int)cap;
        int mt = (mc + 127) / 128;
        gemm_bt<true><<<dim3(16, mt), 256, 0, stream>>>(x_bf + (size_t)r0 * DD, wf1_bf, f1_b, h_bf, mc, DFFD, 768);
        gemm_bt<false><<<dim3(6, mt), 256, 0, stream>>>(h_bf, wf2_bf, f2_b, f_bf + (size_t)r0 * DD, mc, DD, DFFD);
    }

    // x2 = LN2(x + f)
    ln_kernel<2><<<MR, 256, 0, stream>>>(x_bf, nullptr, f_bf, ln2_g, ln2_bb, x2_bf);
    // max-pool + align
    pool_kernel<<<NWIN, 256, 0, stream>>>(x2_bf, pooled, out_align);
    // intent head
    intent_kernel<<<NWIN, 256, 0, stream>>>(pooled, it_w, it_b, out_pred);
    // window_num
    wn_kernel<<<1, 64, 0, stream>>>(seq_lens, out_wn);
}

// Round 2
// 515.725 us; speedup vs baseline: 1.1478x; 1.1478x over previous
//
#include <hip/hip_runtime.h>
#include <hip/hip_bf16.h>

#define BB   16
#define SS   512
#define DD   768
#define NHH  4
#define HDD  192
#define DFFD 2048
#define NID  18
#define NW   510          // S - W + 1
#define NWIN (BB * NW)    // 8160 windows
#define MR   (NWIN * 3)   // 24480 encoder rows

typedef __attribute__((ext_vector_type(8))) short bf16x8;
typedef __attribute__((ext_vector_type(4))) float f32x4;
typedef __hip_bfloat16 bf16;

__device__ __forceinline__ float b2f(bf16 x) { return __bfloat162float(x); }

// ---------------- f32 -> bf16 conversion (vectorized) ----------------
__global__ __launch_bounds__(256) void cvt4_kernel(const float4* __restrict__ in,
                                                   ushort4* __restrict__ out, int n4)
{
    for (int i = blockIdx.x * 256 + threadIdx.x; i < n4; i += gridDim.x * 256) {
        float4 f = in[i];
        ushort4 u;
        u.x = __builtin_bit_cast(unsigned short, __float2bfloat16(f.x));
        u.y = __builtin_bit_cast(unsigned short, __float2bfloat16(f.y));
        u.z = __builtin_bit_cast(unsigned short, __float2bfloat16(f.z));
        u.w = __builtin_bit_cast(unsigned short, __float2bfloat16(f.w));
        out[i] = u;
    }
}

// ---------------- bf16 NT GEMM: C[M,N] = A[M,K] * Bm[N,K]^T + bias ----------------
// m97-style: 128x128 tile, BK=32, 4 waves (2x2 of 64x64), global_load_lds width 16.
// 1-D grid + bijective XCD swizzle (T1, m204): each XCD owns a contiguous chunk of
// row-panels with ALL column tiles of a panel -> A-panel fetched once per XCD.
template<bool RELU>
__global__ void gemm_bt(const bf16* __restrict__ A, const bf16* __restrict__ Bm,
                        const float* __restrict__ bias, bf16* __restrict__ C,
                        int M, int N, int K, int nx)
{
    __shared__ __align__(16) bf16 As[128 * 32];
    __shared__ __align__(16) bf16 Bs[128 * 32];

    // XCD-aware bijective remap of the linear block id
    const int nwg  = gridDim.x;
    const int orig = blockIdx.x;
    const int xcd  = orig & 7;
    const int idx  = orig >> 3;
    const int q8   = nwg >> 3, r8 = nwg & 7;
    const int newid = (xcd < r8 ? xcd * (q8 + 1) : r8 * (q8 + 1) + (xcd - r8) * q8) + idx;
    const int row0 = (newid / nx) * 128;
    const int col0 = (newid % nx) * 128;

    const int tid = threadIdx.x;
    const int ln  = tid & 63;
    const int wv  = tid >> 6;
    const int wm = (wv >> 1) * 64;
    const int wn = (wv & 1) * 64;
    const int lrow = ln & 15;
    const int koff = (ln >> 4) * 8;

    // staging: 512 chunks of 16B per tile; thread t covers chunk t and 256+t
    const int r0 = tid >> 2, c0 = (tid & 3) * 8;
    const int r1 = r0 + 64;
    const bf16* gA0 = A + (size_t)min(row0 + r0, M - 1) * K + c0;
    const bf16* gA1 = A + (size_t)min(row0 + r1, M - 1) * K + c0;
    const bf16* gB0 = Bm + (size_t)(col0 + r0) * K + c0;
    const bf16* gB1 = Bm + (size_t)(col0 + r1) * K + c0;
    bf16* lA0 = As + wv * 512;
    bf16* lA1 = As + 2048 + wv * 512;
    bf16* lB0 = Bs + wv * 512;
    bf16* lB1 = Bs + 2048 + wv * 512;

    f32x4 acc[4][4] = {};

    for (int k0 = 0; k0 < K; k0 += 32) {
        __builtin_amdgcn_global_load_lds((const __attribute__((address_space(1))) void*)(gA0 + k0),
                                         (__attribute__((address_space(3))) void*)lA0, 16, 0, 0);
        __builtin_amdgcn_global_load_lds((const __attribute__((address_space(1))) void*)(gA1 + k0),
                                         (__attribute__((address_space(3))) void*)lA1, 16, 0, 0);
        __builtin_amdgcn_global_load_lds((const __attribute__((address_space(1))) void*)(gB0 + k0),
                                         (__attribute__((address_space(3))) void*)lB0, 16, 0, 0);
        __builtin_amdgcn_global_load_lds((const __attribute__((address_space(1))) void*)(gB1 + k0),
                                         (__attribute__((address_space(3))) void*)lB1, 16, 0, 0);
        __syncthreads();
        bf16x8 av[4], bv[4];
        #pragma unroll
        for (int mi = 0; mi < 4; ++mi)
            av[mi] = *(const bf16x8*)(As + (wm + mi * 16 + lrow) * 32 + koff);
        #pragma unroll
        for (int ni = 0; ni < 4; ++ni)
            bv[ni] = *(const bf16x8*)(Bs + (wn + ni * 16 + lrow) * 32 + koff);
        #pragma unroll
        for (int mi = 0; mi < 4; ++mi)
            #pragma unroll
            for (int ni = 0; ni < 4; ++ni)
                acc[mi][ni] = __builtin_amdgcn_mfma_f32_16x16x32_bf16(av[mi], bv[ni], acc[mi][ni], 0, 0, 0);
        __syncthreads();
    }

    // epilogue: C/D layout col=lane&15, row=(lane>>4)*4+reg
    #pragma unroll
    for (int mi = 0; mi < 4; ++mi) {
        #pragma unroll
        for (int ni = 0; ni < 4; ++ni) {
            const int col = col0 + wn + ni * 16 + lrow;
            const float bb = bias[col];
            #pragma unroll
            for (int r = 0; r < 4; ++r) {
                const int row = row0 + wm + mi * 16 + (ln >> 4) * 4 + r;
                if (row < M) {
                    float v = acc[mi][ni][r] + bb;
                    if (RELU) v = fmaxf(v, 0.0f);
                    C[(size_t)row * N + col] = __float2bfloat16(v);
                }
            }
        }
    }
}

// ---------------- attention over W=3 per (window, head): one wave each ----------------
__global__ __launch_bounds__(256) void attn_kernel(const bf16* __restrict__ qkv, bf16* __restrict__ o)
{
    const int m  = blockIdx.x;
    const int h  = threadIdx.x >> 6;
    const int ln = threadIdx.x & 63;
    const int bb = m / NW, n = m - bb * NW;
    const size_t base = (size_t)(bb * SS + n) * (3 * DD) + h * HDD + ln;
    float q[3][3], k[3][3], v[3][3];
    #pragma unroll
    for (int j = 0; j < 3; ++j)
        #pragma unroll
        for (int t = 0; t < 3; ++t) {
            size_t idx = base + (size_t)j * (3 * DD) + t * 64;
            q[j][t] = b2f(qkv[idx]);
            k[j][t] = b2f(qkv[idx + DD]);
            v[j][t] = b2f(qkv[idx + 2 * DD]);
        }
    float s[3][3];
    #pragma unroll
    for (int i = 0; i < 3; ++i)
        #pragma unroll
        for (int j = 0; j < 3; ++j)
            s[i][j] = q[i][0] * k[j][0] + q[i][1] * k[j][1] + q[i][2] * k[j][2];
    #pragma unroll
    for (int off = 32; off >= 1; off >>= 1)
        #pragma unroll
        for (int i = 0; i < 3; ++i)
            #pragma unroll
            for (int j = 0; j < 3; ++j)
                s[i][j] += __shfl_xor(s[i][j], off);
    const float scale = 0.07216878364870322f; // 1/sqrt(192)
    float p[3][3];
    #pragma unroll
    for (int i = 0; i < 3; ++i) {
        float mx = fmaxf(s[i][0], fmaxf(s[i][1], s[i][2])) * scale;
        float e0 = expf(s[i][0] * scale - mx);
        float e1 = expf(s[i][1] * scale - mx);
        float e2 = expf(s[i][2] * scale - mx);
        float inv = 1.0f / (e0 + e1 + e2);
        p[i][0] = e0 * inv; p[i][1] = e1 * inv; p[i][2] = e2 * inv;
    }
    #pragma unroll
    for (int i = 0; i < 3; ++i)
        #pragma unroll
        for (int t = 0; t < 3; ++t) {
            float ov = p[i][0] * v[0][t] + p[i][1] * v[1][t] + p[i][2] * v[2][t];
            o[(size_t)(m * 3 + i) * DD + h * HDD + t * 64 + ln] = __float2bfloat16(ov);
        }
}

// ---------------- residual + LayerNorm ----------------
// MODE1: xa = hid_bf indexed per-window position; MODE2: xa = x rows direct
template<int MODE>
__global__ __launch_bounds__(256) void ln_kernel(const bf16* __restrict__ xa,
                                                 const bf16* __restrict__ xb,
                                                 const float* __restrict__ gamma,
                                                 const float* __restrict__ beta,
                                                 bf16* __restrict__ out)
{
    const int r = blockIdx.x;
    const int tid = threadIdx.x;
    const size_t rb = (size_t)r * DD;
    size_t ab;
    if (MODE == 1) {
        const int m = r / 3, i = r - m * 3;
        const int bb = m / NW, n = m - bb * NW;
        ab = (size_t)(bb * SS + n + i) * DD;
    } else {
        ab = rb;
    }
    float v[3];
    #pragma unroll
    for (int t = 0; t < 3; ++t) {
        const int d = tid + t * 256;
        v[t] = b2f(xa[ab + d]) + b2f(xb[rb + d]);
    }
    float s1 = v[0] + v[1] + v[2];
    float s2 = v[0] * v[0] + v[1] * v[1] + v[2] * v[2];
    #pragma unroll
    for (int off = 32; off >= 1; off >>= 1) {
        s1 += __shfl_xor(s1, off);
        s2 += __shfl_xor(s2, off);
    }
    __shared__ float red[8];
    const int wvi = tid >> 6, lnn = tid & 63;
    if (lnn == 0) { red[wvi] = s1; red[4 + wvi] = s2; }
    __syncthreads();
    s1 = red[0] + red[1] + red[2] + red[3];
    s2 = red[4] + red[5] + red[6] + red[7];
    const float mean = s1 * (1.0f / 768.0f);
    const float var  = fmaxf(s2 * (1.0f / 768.0f) - mean * mean, 0.0f);
    const float inv  = rsqrtf(var + 1e-5f);
    #pragma unroll
    for (int t = 0; t < 3; ++t) {
        const int d = tid + t * 256;
        out[rb + d] = __float2bfloat16((v[t] - mean) * inv * gamma[d] + beta[d]);
    }
}

// ---------------- fused max-pool + align + intent head ----------------
__global__ __launch_bounds__(256) void pool_intent_kernel(const bf16* __restrict__ x2,
                                                          const float* __restrict__ iw,
                                                          const float* __restrict__ ib,
                                                          float* __restrict__ pred,
                                                          float* __restrict__ align)
{
    const int m = blockIdx.x;
    const int bb = m / NW, n = m - bb * NW;
    const size_t base = (size_t)m * 3 * DD;
    const size_t ab = (size_t)bb * 512 * DD;
    __shared__ float v[DD];
    #pragma unroll
    for (int t = 0; t < 3; ++t) {
        const int d = threadIdx.x + t * 256;
        float v0 = b2f(x2[base + d]);
        float v1 = b2f(x2[base + DD + d]);
        float v2 = b2f(x2[base + 2 * DD + d]);
        float mx = fmaxf(v0, fmaxf(v1, v2));
        v[d] = mx;
        align[ab + (size_t)(n + 1) * DD + d] = mx;
        if (n == 0)      align[ab + d] = mx;
        if (n == NW - 1) align[ab + (size_t)511 * DD + d] = mx;
    }
    __syncthreads();
    const int wvi = threadIdx.x >> 6, lnn = threadIdx.x & 63;
    for (int c = wvi; c < NID; c += 4) {
        float sum = 0.0f;
        #pragma unroll
        for (int t = 0; t < 12; ++t) {
            const int d = lnn + t * 64;
            sum += v[d] * iw[(size_t)c * DD + d];
        }
        #pragma unroll
        for (int off = 32; off >= 1; off >>= 1)
            sum += __shfl_xor(sum, off);
        if (lnn == 0) pred[(size_t)m * NID + c] = sum + ib[c];
    }
}

// ---------------- window_num (as float) ----------------
__global__ void wn_kernel(const int* __restrict__ seq, float* __restrict__ out)
{
    const int t = threadIdx.x;
    if (t < BB) {
        int wn = seq[t] - 2;
        if (wn < 1) wn = 1;
        out[t] = (float)wn;
    }
}

extern "C" void kernel_launch(void* const* d_in, const int* in_sizes, int n_in,
                              void* d_out, int out_size, void* d_ws, size_t ws_size,
                              hipStream_t stream)
{
    const float* hidden   = (const float*)d_in[0];
    const int*   seq_lens = (const int*)d_in[1];
    const float* in_w     = (const float*)d_in[2];
    const float* in_b     = (const float*)d_in[3];
    const float* out_w    = (const float*)d_in[4];
    const float* out_b    = (const float*)d_in[5];
    const float* ln1_g    = (const float*)d_in[6];
    const float* ln1_bb   = (const float*)d_in[7];
    const float* ln2_g    = (const float*)d_in[8];
    const float* ln2_bb   = (const float*)d_in[9];
    const float* f1_w     = (const float*)d_in[10];
    const float* f1_b     = (const float*)d_in[11];
    const float* f2_w     = (const float*)d_in[12];
    const float* f2_b     = (const float*)d_in[13];
    const float* it_w     = (const float*)d_in[14];
    const float* it_b     = (const float*)d_in[15];

    char* ws = (char*)d_ws;
    bf16*  hid_bf   = (bf16*)(ws + 0);          // 12,582,912 B
    bf16*  win_bf   = (bf16*)(ws + 12582912);   //  3,538,944
    bf16*  wout_bf  = (bf16*)(ws + 16121856);   //  1,179,648
    bf16*  wf1_bf   = (bf16*)(ws + 17301504);   //  3,145,728
    bf16*  wf2_bf   = (bf16*)(ws + 20447232);   //  3,145,728
    bf16*  qkv_bf   = (bf16*)(ws + 23592960);   // 37,748,736 (reused for f)
    bf16*  f_bf     = qkv_bf;
    bf16*  o_bf     = (bf16*)(ws + 61341696);   // 37,601,280 (reused for x2)
    bf16*  x2_bf    = o_bf;
    bf16*  oproj_bf = (bf16*)(ws + 98942976);   // 37,601,280
    bf16*  x_bf     = (bf16*)(ws + 136544256);  // 37,601,280
    bf16*  h_bf     = (bf16*)(ws + 174145536);  // FFN hidden (chunked vs ws_size)

    float* out_pred  = (float*)d_out;           // 146880
    float* out_wn    = out_pred + 146880;       // 16
    float* out_align = out_pred + 146896;       // 6,291,456

    // f32 -> bf16
    cvt4_kernel<<<1024, 256, 0, stream>>>((const float4*)hidden, (ushort4*)hid_bf, 1572864);
    cvt4_kernel<<<512, 256, 0, stream>>>((const float4*)in_w,  (ushort4*)win_bf,  442368);
    cvt4_kernel<<<256, 256, 0, stream>>>((const float4*)out_w, (ushort4*)wout_bf, 147456);
    cvt4_kernel<<<512, 256, 0, stream>>>((const float4*)f1_w,  (ushort4*)wf1_bf,  393216);
    cvt4_kernel<<<512, 256, 0, stream>>>((const float4*)f2_w,  (ushort4*)wf2_bf,  393216);

    // QKV (per-position, shared across windows): [8192,768] x [2304,768]^T
    gemm_bt<false><<<18 * 64, 256, 0, stream>>>(hid_bf, win_bf, in_b, qkv_bf, 8192, 2304, 768, 18);
    // attention per (window, head)
    attn_kernel<<<NWIN, 256, 0, stream>>>(qkv_bf, o_bf);
    // out_proj: [24480,768] x [768,768]^T
    gemm_bt<false><<<6 * 192, 256, 0, stream>>>(o_bf, wout_bf, out_b, oproj_bf, MR, 768, 768, 6);
    // x = LN1(win + oproj)  (residual read from bf16 copy of hidden)
    ln_kernel<1><<<MR, 256, 0, stream>>>(hid_bf, oproj_bf, ln1_g, ln1_bb, x_bf);

    // FFN, chunked over rows so the 2048-wide hidden fits in remaining workspace
    size_t avail = ws_size > 174145536ull ? ws_size - 174145536ull : 0;
    long cap = (long)(avail / (DFFD * 2));
    cap = (cap / 128) * 128;
    if (cap < 128) cap = 128;
    if (cap > MR) cap = MR;
    for (int r0 = 0; r0 < MR; r0 += (int)cap) {
        int mc = MR - r0; if (mc > cap) mc = (int)cap;
        int mt = (mc + 127) / 128;
        gemm_bt<true><<<16 * mt, 256, 0, stream>>>(x_bf + (size_t)r0 * DD, wf1_bf, f1_b, h_bf, mc, DFFD, 768, 16);
        gemm_bt<false><<<6 * mt, 256, 0, stream>>>(h_bf, wf2_bf, f2_b, f_bf + (size_t)r0 * DD, mc, DD, DFFD, 6);
    }

    // x2 = LN2(x + f)
    ln_kernel<2><<<MR, 256, 0, stream>>>(x_bf, f_bf, ln2_g, ln2_bb, x2_bf);
    // fused max-pool + align + intent head
    pool_intent_kernel<<<NWIN, 256, 0, stream>>>(x2_bf, it_w, it_b, out_pred, out_align);
    // window_num
    wn_kernel<<<1, 64, 0, stream>>>(seq_lens, out_wn);
}